// Round 10
// baseline (434.745 us; speedup 1.0000x reference)
//
#include <hip/hip_runtime.h>
#include <stdint.h>

#define TOKENS 8192
#define KIN    4096
#define NOUT   11008

// ---- 128x128 GEMM geometry (i8, BK=128 => 128 B/row), 2 blocks/CU ----
#define BM 128
#define BN 128
#define BK 128
#define NT    (KIN / BK)      // 32 K-tiles
#define NTROW (TOKENS / BM)   // 64
#define NTCOL (NOUT / BN)     // 86
#define NWG   (NTROW * NTCOL) // 5504 = 8 XCDs x 688

using i32x4 = __attribute__((ext_vector_type(4))) int;

static __device__ __forceinline__ void gload_lds16(const void* g, void* l) {
  __builtin_amdgcn_global_load_lds((const __attribute__((address_space(1))) void*)g,
                                   (__attribute__((address_space(3))) void*)l,
                                   16, 0, 0);
}

static __device__ __forceinline__ int clamp_q(float f) {
  int q = (int)rintf(f);
  q = q > 127 ? 127 : q;
  q = q < -127 ? -127 : q;
  return q;
}

static __device__ __forceinline__ int pack4(int a, int b, int c, int d) {
  return (a & 0xff) | ((b & 0xff) << 8) | ((c & 0xff) << 16) | ((d & 0xff) << 24);
}

// ---- kernel 1: fused quantization (weight rows then input rows, one launch) ----
// bid < NOUT:  Wq[row] = i8(round(W/scale_w)), scale_w = absmean (f64 reduce)
// bid >= NOUT: Xq[row] = i8(round(X*127/absmax)), scale_x = absmax/127
__global__ __launch_bounds__(256) void quant_fused_k(const float* __restrict__ W,
                                                     const float* __restrict__ X,
                                                     signed char* __restrict__ Wq,
                                                     signed char* __restrict__ Xq,
                                                     float* __restrict__ scale_w,
                                                     float* __restrict__ scale_x) {
  const int bid = blockIdx.x;
  const int t   = threadIdx.x;
  if (bid < NOUT) {
    const int row = bid;
    const float4* wr = reinterpret_cast<const float4*>(W + (size_t)row * KIN);
    float4 v[4];
    double s = 0.0;
#pragma unroll
    for (int i = 0; i < 4; ++i) {
      v[i] = wr[t + i * 256];
      s += fabs((double)v[i].x) + fabs((double)v[i].y) +
           fabs((double)v[i].z) + fabs((double)v[i].w);
    }
#pragma unroll
    for (int off = 32; off > 0; off >>= 1) s += __shfl_down(s, off);
    __shared__ double redd[4];
    if ((t & 63) == 0) redd[t >> 6] = s;
    __syncthreads();
    const float sc = (float)((redd[0] + redd[1] + redd[2] + redd[3]) * (1.0 / KIN));
    if (t == 0) scale_w[row] = sc;
    int* qr = reinterpret_cast<int*>(Wq + (size_t)row * KIN);
#pragma unroll
    for (int i = 0; i < 4; ++i)
      qr[t + i * 256] = pack4(clamp_q(v[i].x / sc), clamp_q(v[i].y / sc),
                              clamp_q(v[i].z / sc), clamp_q(v[i].w / sc));
  } else {
    const int row = bid - NOUT;
    const float4* xr = reinterpret_cast<const float4*>(X + (size_t)row * KIN);
    float4 v[4];
    float amax = 0.f;
#pragma unroll
    for (int i = 0; i < 4; ++i) {
      v[i] = xr[t + i * 256];
      amax = fmaxf(amax, fmaxf(fmaxf(fabsf(v[i].x), fabsf(v[i].y)),
                               fmaxf(fabsf(v[i].z), fabsf(v[i].w))));
    }
#pragma unroll
    for (int off = 32; off > 0; off >>= 1) amax = fmaxf(amax, __shfl_down(amax, off));
    __shared__ float redf[4];
    if ((t & 63) == 0) redf[t >> 6] = amax;
    __syncthreads();
    amax = fmaxf(fmaxf(redf[0], redf[1]), fmaxf(redf[2], redf[3]));
    amax = fmaxf(amax, 1e-30f);
    const float inv = 127.0f / amax;
    if (t == 0) scale_x[row] = amax * (1.0f / 127.0f);
    int* qr = reinterpret_cast<int*>(Xq + (size_t)row * KIN);
#pragma unroll
    for (int i = 0; i < 4; ++i)
      qr[t + i * 256] = pack4(clamp_q(v[i].x * inv), clamp_q(v[i].y * inv),
                              clamp_q(v[i].z * inv), clamp_q(v[i].w * inv));
  }
}

// ---- kernel 2: 128x128x128 i8 GEMM, 2 blocks/CU, 1 barrier per K-tile ----
// out[t,o] = s_x[t]*s_w[o]*(Xq[t,:].Wq[o,:])_i32 + bias[o].  Row-major [row][K] i8.
//
// R10: the lever is THREAD-LEVEL parallelism, not intra-block schedule.
// Diagnosis: per-K-tile cost invariant at ~5050cy across 5 schedule variants
// (R3/R5/R6/R8/R9) because 1 block/CU + barrier-locked waves idle the whole CU
// at every sync point. Fix: 64KB LDS tile -> 2 independent blocks/CU; one
// block's MFMA clusters cover the other's stage/barrier stalls. Tail also
// drops: 5504 blocks = 21.5 rounds (2.3% tail vs 10.4% at 1376).
//
// LDS map (64 KiB): A[buf][128][128B] at buf*16384; B same at 32768+buf*16384.
// Swizzle (both-sides): LDS[r][slot] holds G[r][slot^(r&7)] via pre-swizzled
// global source (linear gload_lds dest); reads XOR the same pattern.
//
// Loop (single barrier per tile):
//   stage(t+1)->nxt   (overwrites tile t-1, consumed before last barrier)
//   read cur frags (16 ds_read) ; MFMA x32
//   vmcnt(0)          (stage issued ~650cy earlier; 97.6% L2-hit => ~free)
//   s_barrier
__global__ __launch_bounds__(256, 2) void gemm_k(const signed char* __restrict__ Xq,
                                                 const signed char* __restrict__ Wq,
                                                 const float* __restrict__ scale_x,
                                                 const float* __restrict__ scale_w,
                                                 const float* __restrict__ bias,
                                                 float* __restrict__ out) {
  __shared__ alignas(16) char lds[65536];

  // ---- supertile swizzle: 5504 = 8 XCDs x 688; per-XCD band of 8 trows;
  // within band: 8trow x 4tcol chunks (21 full chunks = 672) + 8x2 tail (16).
  const int xcd = (int)blockIdx.x & 7;
  const int seq = (int)blockIdx.x >> 3;          // 0..687
  int trow, tcol;
  if (seq < 672) {
    const int chunk = seq >> 5;                  // 0..20
    const int rem   = seq & 31;
    trow = xcd * 8 + (rem >> 2);
    tcol = chunk * 4 + (rem & 3);
  } else {
    const int rem = seq - 672;                   // 0..15
    trow = xcd * 8 + (rem >> 1);
    tcol = 84 + (rem & 1);
  }

  const int tid  = (int)threadIdx.x;
  const int lane = tid & 63;
  const int wave = tid >> 6;   // 0..3
  const int wm   = wave >> 1;  // 0..1 : M half (64 rows)
  const int wn   = wave & 1;   // 0..1 : N half (64 cols)

  // ---- staging lane addresses (inverse-swizzled global source, linear LDS dest) ----
  // wave w stages rows [w*32, w*32+32): gload g covers rows w*32+g*8+(lane>>3),
  // byte slot lane&7 pre-swizzled by row&7 = lane>>3.
  const int l8 = lane >> 3;                          // row within 8-row group
  const size_t rowb = (size_t)KIN;                   // 4096 B per row (i8)
  const int swzl = ((lane & 7) ^ l8) * 16;           // pre-swizzled slot in 128-B row chunk
  const char* gA = (const char*)Xq + (size_t)(trow * BM + wave * 32 + l8) * rowb + swzl;
  const char* gB = (const char*)Wq + (size_t)(tcol * BN + wave * 32 + l8) * rowb + swzl;
  char* lA = lds + wave * 4096;                      // + buf*16384 ; + g*1024
  char* lB = lds + 32768 + wave * 4096;

#define STAGE_TILE(BUF, KS) do {                                             \
    _Pragma("unroll") for (int g = 0; g < 4; ++g)                            \
      gload_lds16(gA + (size_t)(g * 8) * rowb + (KS), lA + (BUF) + g * 1024);\
    _Pragma("unroll") for (int g = 0; g < 4; ++g)                            \
      gload_lds16(gB + (size_t)(g * 8) * rowb + (KS), lB + (BUF) + g * 1024);\
  } while (0)

  // ---- ds_read bases (swizzled) ----
  const int lr = lane & 15;
  const int hi = lane >> 4;                          // 0..3 -> k-slot within 64-B k-slice
  const int swz0 = (hi * 16) ^ ((lr & 7) << 4);
  const int swz[2] = { swz0, swz0 ^ 64 };            // kk=0 / kk=1 (XOR: slot-bit2)
  const char* rdA = lds + wm * 8192 + lr * 128;              // A[buf][wm*64+mf*16+lr][.]
  const char* rdB = lds + 32768 + wn * 8192 + lr * 128;      // B[buf][wn*64+nf*16+lr][.]

  i32x4 acc[4][4];
#pragma unroll
  for (int m = 0; m < 4; ++m)
#pragma unroll
    for (int n = 0; n < 4; ++n) acc[m][n] = (i32x4){0, 0, 0, 0};
  i32x4 afr[4][2], bfr[4][2];

#define SB() __builtin_amdgcn_sched_barrier(0)

#define TILE(T, CUR) do {                                                     \
    if ((T) + 1 < NT) STAGE_TILE((CUR) ^ 16384, (size_t)((T) + 1) * 128);     \
    _Pragma("unroll") for (int mf = 0; mf < 4; ++mf) {                        \
      afr[mf][0] = *(const i32x4*)(rdA + (CUR) + mf * 2048 + swz[0]);         \
      afr[mf][1] = *(const i32x4*)(rdA + (CUR) + mf * 2048 + swz[1]);         \
    }                                                                         \
    _Pragma("unroll") for (int nf = 0; nf < 4; ++nf) {                        \
      bfr[nf][0] = *(const i32x4*)(rdB + (CUR) + nf * 2048 + swz[0]);         \
      bfr[nf][1] = *(const i32x4*)(rdB + (CUR) + nf * 2048 + swz[1]);         \
    }                                                                         \
    __builtin_amdgcn_s_setprio(1);                                            \
    _Pragma("unroll") for (int mf = 0; mf < 4; ++mf)                          \
    _Pragma("unroll") for (int nf = 0; nf < 4; ++nf)                          \
    _Pragma("unroll") for (int kk = 0; kk < 2; ++kk)                          \
      acc[mf][nf] = __builtin_amdgcn_mfma_i32_16x16x64_i8(                    \
          afr[mf][kk], bfr[nf][kk], acc[mf][nf], 0, 0, 0);                    \
    __builtin_amdgcn_s_setprio(0);                                            \
    SB();                                                                     \
    asm volatile("s_waitcnt vmcnt(0)" ::: "memory");                          \
    __builtin_amdgcn_s_barrier();                                             \
    SB();                                                                     \
  } while (0)

  // ---- prologue: stage tile 0 -> buf0; drain; sync ----
  STAGE_TILE(0, 0);
  asm volatile("s_waitcnt vmcnt(0)" ::: "memory");
  __builtin_amdgcn_s_barrier();
  SB();

  for (int tt = 0; tt < NT; tt += 2) {
    TILE(tt,     0);
    TILE(tt + 1, 16384);
  }

  // ---- epilogue: C/D layout col = lane&15, row = (lane>>4)*4 + reg ----
  const int gr_base = trow * BM + wm * 64 + hi * 4;
  const int gc_base = tcol * BN + wn * 64 + lr;
  float sx[4][4];
#pragma unroll
  for (int mf = 0; mf < 4; ++mf)
#pragma unroll
    for (int j = 0; j < 4; ++j) sx[mf][j] = scale_x[gr_base + mf * 16 + j];
#pragma unroll
  for (int nf = 0; nf < 4; ++nf) {
    const int gc = gc_base + nf * 16;
    const float sw = scale_w[gc];
    const float bb = bias[gc];
#pragma unroll
    for (int mf = 0; mf < 4; ++mf) {
      const size_t rb = (size_t)(gr_base + mf * 16) * NOUT + gc;
#pragma unroll
      for (int j = 0; j < 4; ++j)
        __builtin_nontemporal_store((float)acc[mf][nf][j] * (sx[mf][j] * sw) + bb,
                                    &out[rb + (size_t)j * NOUT]);
    }
  }
#undef STAGE_TILE
#undef TILE
#undef SB
}

extern "C" void kernel_launch(void* const* d_in, const int* in_sizes, int n_in,
                              void* d_out, int out_size, void* d_ws, size_t ws_size,
                              hipStream_t stream) {
  const float* X  = (const float*)d_in[0];   // [8192, 4096] fp32
  const float* W  = (const float*)d_in[1];   // [11008, 4096] fp32
  const float* Bi = (const float*)d_in[2];   // [11008] fp32
  float* out = (float*)d_out;                // [8192, 11008] fp32

  const size_t xq_bytes = (size_t)TOKENS * KIN;      // 32 MiB
  const size_t wq_bytes = (size_t)NOUT * KIN;        // 43 MiB
  const size_t need = xq_bytes + wq_bytes + (size_t)(NOUT + TOKENS) * sizeof(float);
  if (ws_size < need) return;  // needs ~76 MB scratch

  char* ws = (char*)d_ws;
  signed char* Xq = (signed char*)ws;
  signed char* Wq = (signed char*)(ws + xq_bytes);
  float* scale_w = (float*)(ws + xq_bytes + wq_bytes);
  float* scale_x = scale_w + NOUT;

  quant_fused_k<<<NOUT + TOKENS, 256, 0, stream>>>(W, X, Wq, Xq, scale_w, scale_x);
  gemm_k<<<NWG, 256, 0, stream>>>(Xq, Wq, scale_x, scale_w, Bi, out);
}